// Round 4
// baseline (2077.938 us; speedup 1.0000x reference)
//
#include <hip/hip_runtime.h>
#include <hip/hip_bf16.h>

#define S_LEN 2048
#define DH    64
#define QB    128
#define KB    64
#define BHN   64
#define LDS_STRIDE 72   // shorts per row (64 + 8 pad) = 144 B

typedef __attribute__((ext_vector_type(8))) short short8;
typedef __attribute__((ext_vector_type(4))) float f32x4;

union Frag {
  short8   s;
  unsigned u[4];
};

// RNE float pair -> packed bf16x2 (compiler emits v_cvt_pk_bf16_f32)
__device__ __forceinline__ unsigned pack2(float a, float b) {
  __hip_bfloat162 h2 = __float22bfloat162_rn(make_float2(a, b));
  unsigned u; __builtin_memcpy(&u, &h2, 4);
  return u;
}

// ---- staging helpers: tile of K (row-major) + V (transposed, rot-swizzled) ----
__device__ __forceinline__ void stage_load(const float* __restrict__ Kg,
                                           const float* __restrict__ Vg,
                                           size_t base, int k0, int tid,
                                           float4 kf[4], float vf[16]) {
  const float4* ks = (const float4*)(Kg + (base + k0) * DH);
  const int u0 = tid, u1 = tid + 256;
  kf[0] = ks[(u0 >> 3) * 16 + (u0 & 7) * 2];
  kf[1] = ks[(u0 >> 3) * 16 + (u0 & 7) * 2 + 1];
  kf[2] = ks[(u1 >> 3) * 16 + (u1 & 7) * 2];
  kf[3] = ks[(u1 >> 3) * 16 + (u1 & 7) * 2 + 1];
  const float* vs = Vg + (base + k0) * DH;
  const int dr = tid & 63, ku0 = tid >> 6;
#pragma unroll
  for (int j = 0; j < 8; ++j) vf[j]     = vs[(8 * ku0 + j) * DH + dr];
#pragma unroll
  for (int j = 0; j < 8; ++j) vf[8 + j] = vs[(8 * (ku0 + 4) + j) * DH + dr];
}

__device__ __forceinline__ void stage_write(short* __restrict__ Kd,
                                            short* __restrict__ Vd, int tid,
                                            const float4 kf[4], const float vf[16]) {
  Frag w;
  const int u0 = tid, u1 = tid + 256;
  w.u[0] = pack2(kf[0].x, kf[0].y); w.u[1] = pack2(kf[0].z, kf[0].w);
  w.u[2] = pack2(kf[1].x, kf[1].y); w.u[3] = pack2(kf[1].z, kf[1].w);
  *(short8*)&Kd[(u0 >> 3) * LDS_STRIDE + (u0 & 7) * 8] = w.s;
  w.u[0] = pack2(kf[2].x, kf[2].y); w.u[1] = pack2(kf[2].z, kf[2].w);
  w.u[2] = pack2(kf[3].x, kf[3].y); w.u[3] = pack2(kf[3].z, kf[3].w);
  *(short8*)&Kd[(u1 >> 3) * LDS_STRIDE + (u1 & 7) * 8] = w.s;

  const int dr = tid & 63, ku0 = tid >> 6, ku1 = ku0 + 4;
  const int rot = (dr >> 2) & 7;
  w.u[0] = pack2(vf[0], vf[1]); w.u[1] = pack2(vf[2], vf[3]);
  w.u[2] = pack2(vf[4], vf[5]); w.u[3] = pack2(vf[6], vf[7]);
  *(short8*)&Vd[dr * LDS_STRIDE + ((ku0 + rot) & 7) * 8] = w.s;
  w.u[0] = pack2(vf[8],  vf[9]);  w.u[1] = pack2(vf[10], vf[11]);
  w.u[2] = pack2(vf[12], vf[13]); w.u[3] = pack2(vf[14], vf[15]);
  *(short8*)&Vd[dr * LDS_STRIDE + ((ku1 + rot) & 7) * 8] = w.s;
}

__global__ __launch_bounds__(256, 4)
void based_attn(const float* __restrict__ Qg,
                const float* __restrict__ Kg,
                const float* __restrict__ Vg,
                float* __restrict__ Og) {
  const int tid  = threadIdx.x;
  const int lane = tid & 63;
  const int wv   = tid >> 6;          // wave 0..3, owns q rows wv*32..wv*32+31
  const int qid  = lane & 15;
  const int g    = lane >> 4;

  const int bh = blockIdx.x;
  const int qt = (int)(gridDim.y - 1) - (int)blockIdx.y;  // heavy blocks first
  const int q0 = qt * QB;

  __shared__ short Klds[2][KB * LDS_STRIDE];   // [k][d] bf16
  __shared__ short Vlds[2][DH * LDS_STRIDE];   // transposed [d][k], rot-swizzled

  const size_t base = (size_t)bh * S_LEN;

  // ---- Q fragments, pre-scaled by 1/sqrt(D)=0.125 ----
  Frag qf[2][2];
  {
    const float SC = 0.125f;
#pragma unroll
    for (int hq = 0; hq < 2; ++hq) {
      const int qrow = q0 + wv * 32 + hq * 16 + qid;
      const float* qp = Qg + (base + qrow) * DH + g * 8;
#pragma unroll
      for (int c = 0; c < 2; ++c) {
        float4 f0 = *(const float4*)(qp + c * 32);
        float4 f1 = *(const float4*)(qp + c * 32 + 4);
        qf[hq][c].u[0] = pack2(f0.x * SC, f0.y * SC);
        qf[hq][c].u[1] = pack2(f0.z * SC, f0.w * SC);
        qf[hq][c].u[2] = pack2(f1.x * SC, f1.y * SC);
        qf[hq][c].u[3] = pack2(f1.z * SC, f1.w * SC);
      }
    }
  }

  // ones-column B fragment -> row sums via MFMA
  Frag ones;
  {
    const unsigned ov = (qid == 0) ? 0x3F803F80u : 0u;
    ones.u[0] = ov; ones.u[1] = ov; ones.u[2] = ov; ones.u[3] = ov;
  }

  f32x4 acc[2][4];
  f32x4 dacc[2];
#pragma unroll
  for (int hq = 0; hq < 2; ++hq) {
    dacc[hq] = (f32x4){0.f, 0.f, 0.f, 0.f};
#pragma unroll
    for (int n = 0; n < 4; ++n) acc[hq][n] = (f32x4){0.f, 0.f, 0.f, 0.f};
  }

  const int nt = 2 * qt + 2;          // causal tile count for this block

  // prologue: stage tile 0 into buffer 0
  {
    float4 kf[4]; float vf[16];
    stage_load(Kg, Vg, base, 0, tid, kf, vf);
    stage_write(Klds[0], Vlds[0], tid, kf, vf);
  }
  __syncthreads();

  for (int t = 0; t < nt; ++t) {
    const int k0 = t * KB;
    const short* Kb = Klds[t & 1];
    const short* Vb = Vlds[t & 1];

    float4 kf[4]; float vf[16];
    const bool havenext = (t + 1 < nt);
    if (havenext) stage_load(Kg, Vg, base, k0 + KB, tid, kf, vf);

    const bool masked = (t >= 2 * qt);

#pragma unroll
    for (int kk = 0; kk < KB; kk += 32) {
      if (q0 + wv * 32 + 31 < k0 + kk) continue;   // wave fully above diagonal

      // K fragments (A operand of S^T)
      short8 aLo[2], aHi[2];
#pragma unroll
      for (int c = 0; c < 2; ++c) {
        aLo[c] = *(const short8*)&Kb[(kk + qid) * LDS_STRIDE + c * 32 + g * 8];
        aHi[c] = *(const short8*)&Kb[(kk + 16 + qid) * LDS_STRIDE + c * 32 + g * 8];
      }

      // S^T = K · Q^T
      f32x4 stL[2], stH[2];
      __builtin_amdgcn_s_setprio(1);
#pragma unroll
      for (int hq = 0; hq < 2; ++hq) {
        stL[hq] = (f32x4){0.f, 0.f, 0.f, 0.f};
        stH[hq] = (f32x4){0.f, 0.f, 0.f, 0.f};
#pragma unroll
        for (int c = 0; c < 2; ++c) {
          stL[hq] = __builtin_amdgcn_mfma_f32_16x16x32_bf16(aLo[c], qf[hq][c].s, stL[hq], 0, 0, 0);
          stH[hq] = __builtin_amdgcn_mfma_f32_16x16x32_bf16(aHi[c], qf[hq][c].s, stH[hq], 0, 0, 0);
        }
      }
      __builtin_amdgcn_s_setprio(0);

      // p = 1 + s + 0.5 s^2, causal mask, pack bf16
      unsigned wrd[2][4];
#pragma unroll
      for (int hq = 0; hq < 2; ++hq) {
        const int qrow = q0 + wv * 32 + hq * 16 + qid;
        float pl[4], ph[4];
#pragma unroll
        for (int r = 0; r < 4; ++r) {
          float sl = stL[hq][r], sh = stH[hq][r];
          pl[r] = fmaf(sl, fmaf(sl, 0.5f, 1.0f), 1.0f);
          ph[r] = fmaf(sh, fmaf(sh, 0.5f, 1.0f), 1.0f);
          if (masked) {
            if (k0 + kk + 4 * g + r > qrow)      pl[r] = 0.f;
            if (k0 + kk + 16 + 4 * g + r > qrow) ph[r] = 0.f;
          }
        }
        wrd[hq][0] = pack2(pl[0], pl[1]);
        wrd[hq][1] = pack2(pl[2], pl[3]);
        wrd[hq][2] = pack2(ph[0], ph[1]);
        wrd[hq][3] = pack2(ph[2], ph[3]);
      }

      // permutation: S^T D-layout (k=4g+r) -> PV A-layout (k=8g+j)
      Frag pa[2];
      {
        const int  sE  = qid + 32 * (g & 1);
        const int  sO  = sE + 16;
        const bool lo2 = (g < 2);
#pragma unroll
        for (int hq = 0; hq < 2; ++hq) {
          int a0 = __shfl((int)wrd[hq][0], sE), b0 = __shfl((int)wrd[hq][2], sE);
          int a1 = __shfl((int)wrd[hq][1], sE), b1 = __shfl((int)wrd[hq][3], sE);
          int a2 = __shfl((int)wrd[hq][0], sO), b2 = __shfl((int)wrd[hq][2], sO);
          int a3 = __shfl((int)wrd[hq][1], sO), b3 = __shfl((int)wrd[hq][3], sO);
          pa[hq].u[0] = (unsigned)(lo2 ? a0 : b0);
          pa[hq].u[1] = (unsigned)(lo2 ? a1 : b1);
          pa[hq].u[2] = (unsigned)(lo2 ? a2 : b2);
          pa[hq].u[3] = (unsigned)(lo2 ? a3 : b3);
        }
      }

      // PV + denominator (V read uses matching rotation swizzle)
      __builtin_amdgcn_s_setprio(1);
#pragma unroll
      for (int n = 0; n < 4; ++n) {
        const int row = n * 16 + qid;
        const int un  = ((kk >> 3) + g + ((row >> 2) & 7)) & 7;
        short8 vb = *(const short8*)&Vb[row * LDS_STRIDE + un * 8];
        acc[0][n] = __builtin_amdgcn_mfma_f32_16x16x32_bf16(pa[0].s, vb, acc[0][n], 0, 0, 0);
        acc[1][n] = __builtin_amdgcn_mfma_f32_16x16x32_bf16(pa[1].s, vb, acc[1][n], 0, 0, 0);
      }
      dacc[0] = __builtin_amdgcn_mfma_f32_16x16x32_bf16(pa[0].s, ones.s, dacc[0], 0, 0, 0);
      dacc[1] = __builtin_amdgcn_mfma_f32_16x16x32_bf16(pa[1].s, ones.s, dacc[1], 0, 0, 0);
      __builtin_amdgcn_s_setprio(0);
    }

    if (havenext) stage_write(Klds[(t + 1) & 1], Vlds[(t + 1) & 1], tid, kf, vf);
    __syncthreads();
  }

  // ---- epilogue: normalize and store fp32 ----
#pragma unroll
  for (int hq = 0; hq < 2; ++hq) {
#pragma unroll
    for (int r = 0; r < 4; ++r) {
      float dn  = __shfl(dacc[hq][r], 16 * g);   // denom(row 4g+r) lives in lane 16g
      float inv = 1.0f / (dn + 1e-6f);
      const int row = q0 + wv * 32 + hq * 16 + 4 * g + r;
      float* op = Og + (base + row) * DH + qid;
#pragma unroll
      for (int n = 0; n < 4; ++n) op[n * 16] = acc[hq][n][r] * inv;
    }
  }
}

extern "C" void kernel_launch(void* const* d_in, const int* in_sizes, int n_in,
                              void* d_out, int out_size, void* d_ws, size_t ws_size,
                              hipStream_t stream) {
  (void)in_sizes; (void)n_in; (void)d_ws; (void)ws_size; (void)out_size;
  const float* Q = (const float*)d_in[0];
  const float* K = (const float*)d_in[1];
  const float* V = (const float*)d_in[2];
  float* O = (float*)d_out;
  dim3 grid(BHN, S_LEN / QB);
  based_attn<<<grid, 256, 0, stream>>>(Q, K, V, O);
}

// Round 5
// 128.111 us; speedup vs baseline: 16.2198x; 16.2198x over previous
//
#include <hip/hip_runtime.h>
#include <hip/hip_bf16.h>

#define S_LEN 2048
#define DH    64
#define QB    128
#define KB    64
#define BHN   64
#define LDS_STRIDE 72   // shorts per row (64 + 8 pad) = 144 B

typedef __attribute__((ext_vector_type(8))) short short8;
typedef __attribute__((ext_vector_type(4))) float f32x4;

union Frag {
  short8   s;
  unsigned u[4];
};

// RNE float pair -> packed bf16x2 (compiler emits v_cvt_pk_bf16_f32)
__device__ __forceinline__ unsigned pack2(float a, float b) {
  __hip_bfloat162 h2 = __float22bfloat162_rn(make_float2(a, b));
  unsigned u; __builtin_memcpy(&u, &h2, 4);
  return u;
}

// Staging: threads 0-127 own K (8 float4 rows), threads 128-255 own V
// (8 float4 = 8 k-rows x 4 d-cols, transposed+rot-swizzled into LDS).
// All state in named registers r0..r7 -> guaranteed SROA.
#define STAGE_LOAD(k0_)                                                        \
  do {                                                                         \
    if (tid < 128) {                                                           \
      const float4* ksrc = (const float4*)(Kg + (base + (size_t)(k0_)) * DH); \
      r0 = ksrc[tid];       r1 = ksrc[tid + 128];                              \
      r2 = ksrc[tid + 256]; r3 = ksrc[tid + 384];                              \
      r4 = ksrc[tid + 512]; r5 = ksrc[tid + 640];                              \
      r6 = ksrc[tid + 768]; r7 = ksrc[tid + 896];                              \
    } else {                                                                   \
      const float4* vsrc = (const float4*)(Vg + (base + (size_t)(k0_)) * DH)  \
                           + ((tid - 128) >> 4) * 128 + ((tid - 128) & 15);    \
      r0 = vsrc[0];  r1 = vsrc[16]; r2 = vsrc[32]; r3 = vsrc[48];              \
      r4 = vsrc[64]; r5 = vsrc[80]; r6 = vsrc[96]; r7 = vsrc[112];             \
    }                                                                          \
  } while (0)

#define STAGE_WRITE(b_)                                                        \
  do {                                                                         \
    if (tid < 128) {                                                           \
      short* Kd = Klds[b_];                                                    \
      const int rb = tid >> 4, c4 = tid & 15;                                  \
      *(uint2*)&Kd[(rb + 0)  * LDS_STRIDE + c4 * 4] = make_uint2(pack2(r0.x, r0.y), pack2(r0.z, r0.w)); \
      *(uint2*)&Kd[(rb + 8)  * LDS_STRIDE + c4 * 4] = make_uint2(pack2(r1.x, r1.y), pack2(r1.z, r1.w)); \
      *(uint2*)&Kd[(rb + 16) * LDS_STRIDE + c4 * 4] = make_uint2(pack2(r2.x, r2.y), pack2(r2.z, r2.w)); \
      *(uint2*)&Kd[(rb + 24) * LDS_STRIDE + c4 * 4] = make_uint2(pack2(r3.x, r3.y), pack2(r3.z, r3.w)); \
      *(uint2*)&Kd[(rb + 32) * LDS_STRIDE + c4 * 4] = make_uint2(pack2(r4.x, r4.y), pack2(r4.z, r4.w)); \
      *(uint2*)&Kd[(rb + 40) * LDS_STRIDE + c4 * 4] = make_uint2(pack2(r5.x, r5.y), pack2(r5.z, r5.w)); \
      *(uint2*)&Kd[(rb + 48) * LDS_STRIDE + c4 * 4] = make_uint2(pack2(r6.x, r6.y), pack2(r6.z, r6.w)); \
      *(uint2*)&Kd[(rb + 56) * LDS_STRIDE + c4 * 4] = make_uint2(pack2(r7.x, r7.y), pack2(r7.z, r7.w)); \
    } else {                                                                   \
      short* Vd = Vlds[b_];                                                    \
      const int l = tid - 128, c4 = l & 15, rp = l >> 4;                       \
      const int slot = (rp + (c4 & 7)) & 7;                                    \
      short* vp = &Vd[(c4 * 4) * LDS_STRIDE + slot * 8];                       \
      Frag w;                                                                  \
      w.u[0] = pack2(r0.x, r1.x); w.u[1] = pack2(r2.x, r3.x);                  \
      w.u[2] = pack2(r4.x, r5.x); w.u[3] = pack2(r6.x, r7.x);                  \
      *(short8*)&vp[0 * LDS_STRIDE] = w.s;                                     \
      w.u[0] = pack2(r0.y, r1.y); w.u[1] = pack2(r2.y, r3.y);                  \
      w.u[2] = pack2(r4.y, r5.y); w.u[3] = pack2(r6.y, r7.y);                  \
      *(short8*)&vp[1 * LDS_STRIDE] = w.s;                                     \
      w.u[0] = pack2(r0.z, r1.z); w.u[1] = pack2(r2.z, r3.z);                  \
      w.u[2] = pack2(r4.z, r5.z); w.u[3] = pack2(r6.z, r7.z);                  \
      *(short8*)&vp[2 * LDS_STRIDE] = w.s;                                     \
      w.u[0] = pack2(r0.w, r1.w); w.u[1] = pack2(r2.w, r3.w);                  \
      w.u[2] = pack2(r4.w, r5.w); w.u[3] = pack2(r6.w, r7.w);                  \
      *(short8*)&vp[3 * LDS_STRIDE] = w.s;                                     \
    }                                                                          \
  } while (0)

__global__ __launch_bounds__(256, 2)
void based_attn(const float* __restrict__ Qg,
                const float* __restrict__ Kg,
                const float* __restrict__ Vg,
                float* __restrict__ Og) {
  const int tid  = threadIdx.x;
  const int lane = tid & 63;
  const int wv   = tid >> 6;          // wave 0..3, owns q rows wv*32..wv*32+31
  const int qid  = lane & 15;
  const int g    = lane >> 4;

  const int bh = blockIdx.x;
  const int qt = (int)(gridDim.y - 1) - (int)blockIdx.y;  // heavy blocks first
  const int q0 = qt * QB;

  __shared__ short Klds[2][KB * LDS_STRIDE];   // [k][d] bf16
  __shared__ short Vlds[2][DH * LDS_STRIDE];   // transposed [d][k], rot-swizzled

  const size_t base = (size_t)bh * S_LEN;

  // ---- Q fragments, pre-scaled by 1/sqrt(D)=0.125 ----
  Frag qf[2][2];
  {
    const float SC = 0.125f;
#pragma unroll
    for (int hq = 0; hq < 2; ++hq) {
      const int qrow = q0 + wv * 32 + hq * 16 + qid;
      const float* qp = Qg + (base + qrow) * DH + g * 8;
#pragma unroll
      for (int c = 0; c < 2; ++c) {
        float4 f0 = *(const float4*)(qp + c * 32);
        float4 f1 = *(const float4*)(qp + c * 32 + 4);
        qf[hq][c].u[0] = pack2(f0.x * SC, f0.y * SC);
        qf[hq][c].u[1] = pack2(f0.z * SC, f0.w * SC);
        qf[hq][c].u[2] = pack2(f1.x * SC, f1.y * SC);
        qf[hq][c].u[3] = pack2(f1.z * SC, f1.w * SC);
      }
    }
  }

  // ones-column B fragment -> row sums via MFMA
  Frag ones;
  {
    const unsigned ov = (qid == 0) ? 0x3F803F80u : 0u;
    ones.u[0] = ov; ones.u[1] = ov; ones.u[2] = ov; ones.u[3] = ov;
  }

  f32x4 acc[2][4];
  f32x4 dacc[2];
#pragma unroll
  for (int hq = 0; hq < 2; ++hq) {
    dacc[hq] = (f32x4){0.f, 0.f, 0.f, 0.f};
#pragma unroll
    for (int n = 0; n < 4; ++n) acc[hq][n] = (f32x4){0.f, 0.f, 0.f, 0.f};
  }

  const int nt = 2 * qt + 2;          // causal tile count for this block

  float4 r0, r1, r2, r3, r4, r5, r6, r7;   // staging registers (named -> SROA)

  // prologue: stage tile 0 into buffer 0
  STAGE_LOAD(0);
  STAGE_WRITE(0);
  __syncthreads();

  for (int t = 0; t < nt; ++t) {
    const int k0 = t * KB;
    const short* Kb = Klds[t & 1];
    const short* Vb = Vlds[t & 1];

    const bool havenext = (t + 1 < nt);
    if (havenext) STAGE_LOAD(k0 + KB);   // issue early; latency hides under MFMA

    const bool masked = (t >= 2 * qt);

#pragma unroll
    for (int kk = 0; kk < KB; kk += 32) {
      if (q0 + wv * 32 + 31 < k0 + kk) continue;   // wave fully above diagonal

      // K fragments (A operand of S^T)
      short8 aLo[2], aHi[2];
#pragma unroll
      for (int c = 0; c < 2; ++c) {
        aLo[c] = *(const short8*)&Kb[(kk + qid) * LDS_STRIDE + c * 32 + g * 8];
        aHi[c] = *(const short8*)&Kb[(kk + 16 + qid) * LDS_STRIDE + c * 32 + g * 8];
      }

      // S^T = K · Q^T
      f32x4 stL[2], stH[2];
      __builtin_amdgcn_s_setprio(1);
#pragma unroll
      for (int hq = 0; hq < 2; ++hq) {
        stL[hq] = (f32x4){0.f, 0.f, 0.f, 0.f};
        stH[hq] = (f32x4){0.f, 0.f, 0.f, 0.f};
#pragma unroll
        for (int c = 0; c < 2; ++c) {
          stL[hq] = __builtin_amdgcn_mfma_f32_16x16x32_bf16(aLo[c], qf[hq][c].s, stL[hq], 0, 0, 0);
          stH[hq] = __builtin_amdgcn_mfma_f32_16x16x32_bf16(aHi[c], qf[hq][c].s, stH[hq], 0, 0, 0);
        }
      }
      __builtin_amdgcn_s_setprio(0);

      // p = 1 + s + 0.5 s^2, causal mask, pack bf16
      unsigned wrd[2][4];
#pragma unroll
      for (int hq = 0; hq < 2; ++hq) {
        const int qrow = q0 + wv * 32 + hq * 16 + qid;
        float pl[4], ph[4];
#pragma unroll
        for (int r = 0; r < 4; ++r) {
          float sl = stL[hq][r], sh = stH[hq][r];
          pl[r] = fmaf(sl, fmaf(sl, 0.5f, 1.0f), 1.0f);
          ph[r] = fmaf(sh, fmaf(sh, 0.5f, 1.0f), 1.0f);
          if (masked) {
            if (k0 + kk + 4 * g + r > qrow)      pl[r] = 0.f;
            if (k0 + kk + 16 + 4 * g + r > qrow) ph[r] = 0.f;
          }
        }
        wrd[hq][0] = pack2(pl[0], pl[1]);
        wrd[hq][1] = pack2(pl[2], pl[3]);
        wrd[hq][2] = pack2(ph[0], ph[1]);
        wrd[hq][3] = pack2(ph[2], ph[3]);
      }

      // permutation: S^T D-layout (k=4g+r) -> PV A-layout (k=8g+j)
      Frag pa[2];
      {
        const int  sE  = qid + 32 * (g & 1);
        const int  sO  = sE + 16;
        const bool lo2 = (g < 2);
#pragma unroll
        for (int hq = 0; hq < 2; ++hq) {
          int a0 = __shfl((int)wrd[hq][0], sE), b0 = __shfl((int)wrd[hq][2], sE);
          int a1 = __shfl((int)wrd[hq][1], sE), b1 = __shfl((int)wrd[hq][3], sE);
          int a2 = __shfl((int)wrd[hq][0], sO), b2 = __shfl((int)wrd[hq][2], sO);
          int a3 = __shfl((int)wrd[hq][1], sO), b3 = __shfl((int)wrd[hq][3], sO);
          pa[hq].u[0] = (unsigned)(lo2 ? a0 : b0);
          pa[hq].u[1] = (unsigned)(lo2 ? a1 : b1);
          pa[hq].u[2] = (unsigned)(lo2 ? a2 : b2);
          pa[hq].u[3] = (unsigned)(lo2 ? a3 : b3);
        }
      }

      // PV + denominator (V read uses matching rotation swizzle)
      __builtin_amdgcn_s_setprio(1);
#pragma unroll
      for (int n = 0; n < 4; ++n) {
        const int row = n * 16 + qid;
        const int un  = ((kk >> 3) + g + ((row >> 2) & 7)) & 7;
        short8 vb = *(const short8*)&Vb[row * LDS_STRIDE + un * 8];
        acc[0][n] = __builtin_amdgcn_mfma_f32_16x16x32_bf16(pa[0].s, vb, acc[0][n], 0, 0, 0);
        acc[1][n] = __builtin_amdgcn_mfma_f32_16x16x32_bf16(pa[1].s, vb, acc[1][n], 0, 0, 0);
      }
      dacc[0] = __builtin_amdgcn_mfma_f32_16x16x32_bf16(pa[0].s, ones.s, dacc[0], 0, 0, 0);
      dacc[1] = __builtin_amdgcn_mfma_f32_16x16x32_bf16(pa[1].s, ones.s, dacc[1], 0, 0, 0);
      __builtin_amdgcn_s_setprio(0);
    }

    if (havenext) STAGE_WRITE((t + 1) & 1);  // convert+write after compute
    __syncthreads();
  }

  // ---- epilogue: normalize and store fp32 ----
#pragma unroll
  for (int hq = 0; hq < 2; ++hq) {
#pragma unroll
    for (int r = 0; r < 4; ++r) {
      float dn  = __shfl(dacc[hq][r], 16 * g);   // denom(row 4g+r) lives in lane 16g
      float inv = 1.0f / (dn + 1e-6f);
      const int row = q0 + wv * 32 + hq * 16 + 4 * g + r;
      float* op = Og + (base + row) * DH + qid;
#pragma unroll
      for (int n = 0; n < 4; ++n) op[n * 16] = acc[hq][n][r] * inv;
    }
  }
}

extern "C" void kernel_launch(void* const* d_in, const int* in_sizes, int n_in,
                              void* d_out, int out_size, void* d_ws, size_t ws_size,
                              hipStream_t stream) {
  (void)in_sizes; (void)n_in; (void)d_ws; (void)ws_size; (void)out_size;
  const float* Q = (const float*)d_in[0];
  const float* K = (const float*)d_in[1];
  const float* V = (const float*)d_in[2];
  float* O = (float*)d_out;
  dim3 grid(BHN, S_LEN / QB);
  based_attn<<<grid, 256, 0, stream>>>(Q, K, V, O);
}